// Round 5
// baseline (190.959 us; speedup 1.0000x reference)
//
#include <hip/hip_runtime.h>
#include <hip/hip_bf16.h>

typedef __attribute__((ext_vector_type(8))) short bf16x8;
typedef __attribute__((ext_vector_type(4))) float f32x4;
typedef __attribute__((ext_vector_type(4))) short short4v;

#define D128 128
#define IMG_SHORTS 16384          // one W frag-image: 32 frags x 64 lanes x 8 bf16 = 32 KB
#define H_OFF 65536               // H starts at 128 KiB into d_ws (in shorts)

__device__ __forceinline__ short f2bf(float f) {
    union { float f; unsigned u; } v; v.f = f;
    unsigned r = (v.u + 0x7FFFu + ((v.u >> 16) & 1u)) >> 16;  // RNE
    return (short)r;
}

__device__ __forceinline__ short f2bf_h(float f) {
    __hip_bfloat16 h = __float2bfloat16(f);
    short s;
    __builtin_memcpy(&s, &h, sizeof(short));
    return s;
}

__device__ __forceinline__ bf16x8 pack8(float4 a, float4 b) {
    bf16x8 r;
    r[0] = f2bf_h(a.x); r[1] = f2bf_h(a.y); r[2] = f2bf_h(a.z); r[3] = f2bf_h(a.w);
    r[4] = f2bf_h(b.x); r[5] = f2bf_h(b.y); r[6] = f2bf_h(b.z); r[7] = f2bf_h(b.w);
    return r;
}

__device__ __forceinline__ f32x4 bf4_to_f32(short4v s) {
    f32x4 r;
#pragma unroll
    for (int j = 0; j < 4; ++j) {
        unsigned u = ((unsigned)(unsigned short)s[j]) << 16;
        float f; __builtin_memcpy(&f, &u, 4);
        r[j] = f;
    }
    return r;
}

__device__ __forceinline__ void gload_lds16(const short* g, short* l) {
    __builtin_amdgcn_global_load_lds(
        (const __attribute__((address_space(1))) unsigned int*)(const void*)g,
        (__attribute__((address_space(3))) unsigned int*)(void*)l, 16, 0, 0);
}

// W (3*128 x 128 fp32 row-major) -> 3 A-operand fragment images (src,dst,e):
// img[c][frag=mt*4+ks][lane][j] = W[c*128 + ks*32 + (lane>>4)*8 + j][mt*16 + (lane&15)]
__global__ __launch_bounds__(256) void wt_kernel(const float* __restrict__ W,
                                                 short* __restrict__ Wimg) {
    const int c    = blockIdx.x >> 3;
    const int frag = (blockIdx.x & 7) * 4 + (threadIdx.x >> 6);
    const int lane = threadIdx.x & 63;
    const int mt = frag >> 2, ks = frag & 3;
    const int m  = mt * 16 + (lane & 15);
    const int k0 = ks * 32 + (lane >> 4) * 8;
    bf16x8 v;
#pragma unroll
    for (int j = 0; j < 8; ++j)
        v[j] = f2bf(W[(size_t)(c * 128 + k0 + j) * D128 + m]);
    *reinterpret_cast<bf16x8*>(
        &Wimg[((size_t)c * 32 + frag) * 64 * 8 + (size_t)lane * 8]) = v;
}

// Dense: H[n] = [ x[n] @ W_src | x[n] @ W_dst ]  (bf16, 256 cols)
// 512 thr = 8 waves; lane owns row rn = r0 + w*16 + (lane&15); 128 rows/block.
__global__ __launch_bounds__(512) void ha_kernel(const float* __restrict__ x,
                                                 const short* __restrict__ Wimg,
                                                 short* __restrict__ H,
                                                 int Nrows) {
    __shared__ short Ws[2 * IMG_SHORTS];   // 64 KB: src + dst images

    const int tid  = threadIdx.x;
    const int lane = tid & 63;
    const int w    = tid >> 6;
    const int lhi  = lane >> 4;
    const int rn   = blockIdx.x * 128 + w * 16 + (lane & 15);
    const bool valid = rn < Nrows;
    const int  rl  = valid ? rn : (Nrows - 1);

    // stage both W images: 4096 x 16B units, 8 per thread, linear both sides
#pragma unroll
    for (int jj = 0; jj < 8; ++jj) {
        int unit = jj * 512 + tid;
        gload_lds16(Wimg + (size_t)unit * 8, &Ws[unit * 8]);
    }
    asm volatile("" ::: "memory");

    const float* px = x + (size_t)rl * D128;
    float4 ev[8];
#pragma unroll
    for (int ks = 0; ks < 4; ++ks) {
        ev[2 * ks]     = reinterpret_cast<const float4*>(px + ks * 32 + lhi * 8)[0];
        ev[2 * ks + 1] = reinterpret_cast<const float4*>(px + ks * 32 + lhi * 8)[1];
    }
    asm volatile("" ::: "memory");
    asm volatile("s_waitcnt vmcnt(8)" ::: "memory");   // drain stage; x loads fly
    __builtin_amdgcn_s_barrier();

    bf16x8 bx[4];
#pragma unroll
    for (int ks = 0; ks < 4; ++ks) bx[ks] = pack8(ev[2 * ks], ev[2 * ks + 1]);

    f32x4 acc[16];
#pragma unroll
    for (int i = 0; i < 16; ++i) acc[i] = (f32x4){0.f, 0.f, 0.f, 0.f};

#pragma unroll
    for (int c = 0; c < 2; ++c)
#pragma unroll
        for (int ks = 0; ks < 4; ++ks)
#pragma unroll
            for (int mt = 0; mt < 8; ++mt) {
                bf16x8 a = *reinterpret_cast<const bf16x8*>(
                    &Ws[((c * 32 + mt * 4 + ks) * 64 + lane) * 8]);
                acc[c * 8 + mt] = __builtin_amdgcn_mfma_f32_16x16x32_bf16(
                    a, bx[ks], acc[c * 8 + mt], 0, 0, 0);
            }

    if (valid) {
        short* ph = H + (size_t)rn * 256 + lhi * 4;
#pragma unroll
        for (int i = 0; i < 16; ++i) {
            short4v sv;
            sv[0] = f2bf_h(acc[i][0]); sv[1] = f2bf_h(acc[i][1]);
            sv[2] = f2bf_h(acc[i][2]); sv[3] = f2bf_h(acc[i][3]);
            // i = c*8 + mt -> col block c*128 + mt*16
            *reinterpret_cast<short4v*>(ph + (i >> 3) * 128 + (i & 7) * 16) = sv;
        }
    }
}

// Main: out[r] = e[r] @ W_e + H_src[src[r]] + H_dst[dst[r]]
// 512 thr = 8 waves; lane owns row rn = r0 + w*16 + (lane&15); 128 rows/block.
__global__ __launch_bounds__(512) void eb_kernel(const float* __restrict__ e,
                                                 const short* __restrict__ Wimg,
                                                 const short* __restrict__ H,
                                                 const int*  __restrict__ src_idx,
                                                 const int*  __restrict__ dst_idx,
                                                 float* __restrict__ out) {
    __shared__ short Ws[IMG_SHORTS];   // 32 KB: W_e image

    const int tid  = threadIdx.x;
    const int lane = tid & 63;
    const int w    = tid >> 6;
    const int lhi  = lane >> 4;
    const int rn   = blockIdx.x * 128 + w * 16 + (lane & 15);

    // idx first (needed for gather addresses)
    const int si = src_idx[rn];
    const int di = dst_idx[rn];
    asm volatile("" ::: "memory");

    // stage W_e image: 2048 x 16B units, 4 per thread
#pragma unroll
    for (int jj = 0; jj < 4; ++jj) {
        int unit = jj * 512 + tid;
        gload_lds16(Wimg + (size_t)unit * 8, &Ws[unit * 8]);
    }
    asm volatile("" ::: "memory");

    // e row loads (independent of idx)
    const float* pe = e + (size_t)rn * D128;
    float4 ev[8];
#pragma unroll
    for (int ks = 0; ks < 4; ++ks) {
        ev[2 * ks]     = reinterpret_cast<const float4*>(pe + ks * 32 + lhi * 8)[0];
        ev[2 * ks + 1] = reinterpret_cast<const float4*>(pe + ks * 32 + lhi * 8)[1];
    }
    asm volatile("" ::: "memory");

    // H gathers: this lane needs cols mt*16 + lhi*4 .. +3 of both halves
    const short* phs = H + (size_t)si * 256 + lhi * 4;         // src half (cols 0..127)
    const short* phd = H + (size_t)di * 256 + 128 + lhi * 4;   // dst half (cols 128..255)
    short4v hs[8], hd[8];
#pragma unroll
    for (int mt = 0; mt < 8; ++mt) {
        hs[mt] = *reinterpret_cast<const short4v*>(phs + mt * 16);
        hd[mt] = *reinterpret_cast<const short4v*>(phd + mt * 16);
    }
    asm volatile("" ::: "memory");
    // outstanding: 4 stage (oldest) + 8 e + 16 H = 28; drain stage only.
    asm volatile("s_waitcnt vmcnt(24)" ::: "memory");
    __builtin_amdgcn_s_barrier();

    bf16x8 bx[4];
#pragma unroll
    for (int ks = 0; ks < 4; ++ks) bx[ks] = pack8(ev[2 * ks], ev[2 * ks + 1]);

    f32x4 acc[8];
#pragma unroll
    for (int mt = 0; mt < 8; ++mt) acc[mt] = (f32x4){0.f, 0.f, 0.f, 0.f};

#pragma unroll
    for (int ks = 0; ks < 4; ++ks)
#pragma unroll
        for (int mt = 0; mt < 8; ++mt) {
            bf16x8 a = *reinterpret_cast<const bf16x8*>(
                &Ws[((mt * 4 + ks) * 64 + lane) * 8]);
            acc[mt] = __builtin_amdgcn_mfma_f32_16x16x32_bf16(a, bx[ks], acc[mt], 0, 0, 0);
        }

    float* po = out + (size_t)rn * D128 + lhi * 4;
#pragma unroll
    for (int mt = 0; mt < 8; ++mt) {
        f32x4 r = acc[mt] + bf4_to_f32(hs[mt]) + bf4_to_f32(hd[mt]);
        *reinterpret_cast<float4*>(po + mt * 16) = *(float4*)&r;
    }
}

extern "C" void kernel_launch(void* const* d_in, const int* in_sizes, int n_in,
                              void* d_out, int out_size, void* d_ws, size_t ws_size,
                              hipStream_t stream) {
    const float* x = (const float*)d_in[0];
    const float* e = (const float*)d_in[1];
    const float* W = (const float*)d_in[2];
    const int* src = (const int*)d_in[3];
    const int* dst = (const int*)d_in[4];
    float* out = (float*)d_out;

    short* Wimg = (short*)d_ws;                 // 3 x 32 KB frag images
    short* H    = (short*)d_ws + H_OFF;         // 100000 x 256 bf16 = 51.2 MB

    const int N = in_sizes[0] / D128;           // 100000
    const int E = in_sizes[3];                  // 400000

    wt_kernel<<<24, 256, 0, stream>>>(W, Wimg);
    ha_kernel<<<(N + 127) / 128, 512, 0, stream>>>(x, Wimg, H, N);
    eb_kernel<<<E / 128, 512, 0, stream>>>(e, Wimg + 2 * IMG_SHORTS, H, src, dst, out);
}